// Round 1
// baseline (1756.668 us; speedup 1.0000x reference)
//
#include <hip/hip_runtime.h>
#include <stdint.h>

#define HID 1024
#define NHEADS 16
#define HDIM 64
#define BB 4
#define SS 2048
#define MROWS (BB * SS) /* 8192 */

typedef float f32x4 __attribute__((ext_vector_type(4)));
typedef short s16x8 __attribute__((ext_vector_type(8)));
typedef __bf16 b16x8 __attribute__((ext_vector_type(8)));
typedef unsigned short us16x4 __attribute__((ext_vector_type(4)));

__device__ __forceinline__ unsigned short f2bf(float f) {
  union { float f; unsigned u; } c; c.f = f;
  unsigned r = (c.u + 0x7fffu + ((c.u >> 16) & 1u)) >> 16;  // RNE
  return (unsigned short)r;
}

// ---- MFMA wrapper: tolerant to builtin operand type (short8 vs bf16x8) ----
template <typename T>
static __device__ auto mfma_try(T a, T b, f32x4 c, int)
    -> decltype(__builtin_amdgcn_mfma_f32_16x16x32_bf16(a, b, c, 0, 0, 0)) {
  return __builtin_amdgcn_mfma_f32_16x16x32_bf16(a, b, c, 0, 0, 0);
}
template <typename T>
static __device__ f32x4 mfma_try(T a, T b, f32x4 c, long) {
  return __builtin_amdgcn_mfma_f32_16x16x32_bf16(
      __builtin_bit_cast(b16x8, a), __builtin_bit_cast(b16x8, b), c, 0, 0, 0);
}
__device__ __forceinline__ f32x4 MFMA(s16x8 a, s16x8 b, f32x4 c) {
  return mfma_try(a, b, c, 0);
}

__device__ __forceinline__ void gload16(const void* g, void* l) {
  __builtin_amdgcn_global_load_lds(
      (const __attribute__((address_space(1))) void*)g,
      (__attribute__((address_space(3))) void*)l, 16, 0, 0);
}

// ---------------- convert fp32 -> bf16 (vectorized) ----------------
__global__ __launch_bounds__(256) void to_bf16(const float* __restrict__ in,
                                               unsigned short* __restrict__ out,
                                               int n4) {
  int i = blockIdx.x * blockDim.x + threadIdx.x;
  for (; i < n4; i += gridDim.x * blockDim.x) {
    float4 v = ((const float4*)in)[i];
    us16x4 o;
    o[0] = f2bf(v.x); o[1] = f2bf(v.y); o[2] = f2bf(v.z); o[3] = f2bf(v.w);
    ((us16x4*)out)[i] = o;
  }
}

// ---------------- W [R][C] fp32 -> WT [C][R] bf16 ----------------
__global__ __launch_bounds__(256) void transpose_w(const float* __restrict__ W,
                                                   unsigned short* __restrict__ WT,
                                                   int R, int C) {
  __shared__ float t[32][33];
  const int c0 = blockIdx.x * 32, r0 = blockIdx.y * 32;
  const int tx = threadIdx.x, ty = threadIdx.y;
  for (int j = ty; j < 32; j += 8) t[j][tx] = W[(size_t)(r0 + j) * C + c0 + tx];
  __syncthreads();
  for (int j = ty; j < 32; j += 8)
    WT[(size_t)(c0 + j) * R + r0 + tx] = f2bf(t[tx][j]);
}

// ---------------- GEMM: C[M,128-tile] = A[M,1024] * BT[N,1024]^T + bias ----------------
// m97 structure: 128x128 tile, 4 waves (2x2), BK=32, global_load_lds(16B)
template <int OUT_F32>
__global__ __launch_bounds__(256) void gemm_bt_128(
    const unsigned short* __restrict__ A, const unsigned short* __restrict__ BT,
    const float* __restrict__ bias, void* __restrict__ Cout, float scale) {
  __shared__ __align__(16) unsigned short sA[128 * 32];
  __shared__ __align__(16) unsigned short sB[128 * 32];
  const int tid = threadIdx.x;
  const int wid = tid >> 6, lane = tid & 63, g = lane >> 4, ln = lane & 15;
  const int m0 = blockIdx.x * 128, n0 = blockIdx.y * 128;
  const int wm = (wid >> 1) * 64, wn = (wid & 1) * 64;
  const int trow = tid >> 2, tkb = (tid & 3) * 8;

  f32x4 acc[4][4];
#pragma unroll
  for (int i = 0; i < 4; i++)
#pragma unroll
    for (int j = 0; j < 4; j++) acc[i][j] = {0.f, 0.f, 0.f, 0.f};

  const size_t abase = (size_t)(m0 + trow) * HID + tkb;
  const size_t bbase = (size_t)(n0 + trow) * HID + tkb;

  for (int k0 = 0; k0 < HID; k0 += 32) {
    __syncthreads();
    gload16(A + abase + k0, (char*)sA + tid * 16);
    gload16(A + abase + (size_t)64 * HID + k0, (char*)sA + 4096 + tid * 16);
    gload16(BT + bbase + k0, (char*)sB + tid * 16);
    gload16(BT + bbase + (size_t)64 * HID + k0, (char*)sB + 4096 + tid * 16);
    __syncthreads();
    s16x8 af[4], bfr[4];
#pragma unroll
    for (int i = 0; i < 4; i++)
      af[i] = *(const s16x8*)&sA[(wm + i * 16 + ln) * 32 + 8 * g];
#pragma unroll
    for (int i = 0; i < 4; i++)
      bfr[i] = *(const s16x8*)&sB[(wn + i * 16 + ln) * 32 + 8 * g];
#pragma unroll
    for (int i = 0; i < 4; i++)
#pragma unroll
      for (int j = 0; j < 4; j++) acc[i][j] = MFMA(af[i], bfr[j], acc[i][j]);
  }
#pragma unroll
  for (int i = 0; i < 4; i++) {
#pragma unroll
    for (int j = 0; j < 4; j++) {
      const int col = n0 + wn + j * 16 + ln;
      const float bcol = bias[col];
#pragma unroll
      for (int r = 0; r < 4; r++) {
        const int row = m0 + wm + i * 16 + 4 * g + r;
        const float v = (acc[i][j][r] + bcol) * scale;
        if (OUT_F32)
          ((float*)Cout)[(size_t)row * HID + col] = v;
        else
          ((unsigned short*)Cout)[(size_t)row * HID + col] = f2bf(v);
      }
    }
  }
}

// ---------------- GEMM: C[M,64] = A[M,1024] * BT[64,1024]^T + bias ----------------
// VT_OUT=1 writes transposed per-batch: out[(b*64+d)*2048 + s]
template <int VT_OUT>
__global__ __launch_bounds__(256) void gemm_bt_64(
    const unsigned short* __restrict__ A, const unsigned short* __restrict__ BT,
    const float* __restrict__ bias, unsigned short* __restrict__ Cout) {
  __shared__ __align__(16) unsigned short sA[128 * 32];
  __shared__ __align__(16) unsigned short sB[64 * 32];
  const int tid = threadIdx.x;
  const int wid = tid >> 6, lane = tid & 63, g = lane >> 4, ln = lane & 15;
  const int m0 = blockIdx.x * 128;
  const int wm = (wid >> 1) * 64, wn = (wid & 1) * 32;
  const int trow = tid >> 2, tkb = (tid & 3) * 8;

  f32x4 acc[4][2];
#pragma unroll
  for (int i = 0; i < 4; i++)
#pragma unroll
    for (int j = 0; j < 2; j++) acc[i][j] = {0.f, 0.f, 0.f, 0.f};

  const size_t abase = (size_t)(m0 + trow) * HID + tkb;
  const size_t bbase = (size_t)trow * HID + tkb;  // BT has 64 rows

  for (int k0 = 0; k0 < HID; k0 += 32) {
    __syncthreads();
    gload16(A + abase + k0, (char*)sA + tid * 16);
    gload16(A + abase + (size_t)64 * HID + k0, (char*)sA + 4096 + tid * 16);
    if (trow < 64) {}  // all 256 threads used: 64 rows * 4 chunks
    gload16(BT + bbase + k0, (char*)sB + tid * 16);
    __syncthreads();
    s16x8 af[4], bfr[2];
#pragma unroll
    for (int i = 0; i < 4; i++)
      af[i] = *(const s16x8*)&sA[(wm + i * 16 + ln) * 32 + 8 * g];
#pragma unroll
    for (int j = 0; j < 2; j++)
      bfr[j] = *(const s16x8*)&sB[(wn + j * 16 + ln) * 32 + 8 * g];
#pragma unroll
    for (int i = 0; i < 4; i++)
#pragma unroll
      for (int j = 0; j < 2; j++) acc[i][j] = MFMA(af[i], bfr[j], acc[i][j]);
  }
#pragma unroll
  for (int i = 0; i < 4; i++) {
#pragma unroll
    for (int j = 0; j < 2; j++) {
      const int col = wn + j * 16 + ln;
      const float bcol = bias[col];
#pragma unroll
      for (int r = 0; r < 4; r++) {
        const int row = m0 + wm + i * 16 + 4 * g + r;
        const float v = acc[i][j][r] + bcol;
        if (VT_OUT)
          Cout[((size_t)(row >> 11) * HDIM + col) * SS + (row & 2047)] = f2bf(v);
        else
          Cout[(size_t)row * HDIM + col] = f2bf(v);
      }
    }
  }
}

// ---------------- fused two-pass MQA attention ----------------
// grid (32 qtiles, 16 heads, 4 batch), 256 thr (4 waves x 16 q-rows)
__global__ __launch_bounds__(256) void attn_kernel(
    const unsigned short* __restrict__ Q,   // [B,S,HID] bf16, pre-scaled 1/8
    const unsigned short* __restrict__ Qi,
    const unsigned short* __restrict__ K,   // [B,S,64] bf16
    const unsigned short* __restrict__ Ki,
    const unsigned short* __restrict__ VT,  // [B,64,S] bf16
    const unsigned short* __restrict__ ViT,
    const int* __restrict__ mask,           // [B,S]
    float* __restrict__ attn_out,           // [B,H,S,S] fp32
    unsigned short* __restrict__ X) {       // [B,S,HID] bf16
  __shared__ __align__(16) char smK[4096];
  __shared__ __align__(16) char smKi[4096];
  __shared__ __align__(16) char smV[4096];
  __shared__ __align__(16) char smVi[4096];
  __shared__ __align__(16) char smP1[4][1280];
  __shared__ __align__(16) char smP2[4][1280];

  const int b = blockIdx.z, h = blockIdx.y, qt = blockIdx.x;
  const int tid = threadIdx.x, wid = tid >> 6, lane = tid & 63;
  const int g = lane >> 4, ln = lane & 15;
  const int q0 = qt * 64 + wid * 16;

  // hoist Q fragments from global (A-frag: m=ln, k=8g+e)
  const size_t qoff = ((size_t)(b * SS + q0 + ln)) * HID + h * HDIM;
  const s16x8 aq0 = *(const s16x8*)(Q + qoff + 8 * g);
  const s16x8 aq1 = *(const s16x8*)(Q + qoff + 32 + 8 * g);
  const s16x8 ai0 = *(const s16x8*)(Qi + qoff + 8 * g);
  const s16x8 ai1 = *(const s16x8*)(Qi + qoff + 32 + 8 * g);

  const char* Kb = (const char*)(K + (size_t)b * SS * HDIM);
  const char* Kib = (const char*)(Ki + (size_t)b * SS * HDIM);
  const char* Vb = (const char*)(VT + (size_t)b * HDIM * SS);
  const char* Vib = (const char*)(ViT + (size_t)b * HDIM * SS);
  const int* mb = mask + b * SS;

  // staging addresses (inverse-swizzled global source, linear LDS dest)
  const int beta = tid * 16;
  const int klin = beta ^ (((beta >> 7) & 7) << 4);  // involution, rows=128B
  const int vlin = beta ^ (((beta >> 7) & 3) << 4);  // involution, rows=64B
  const int vd = vlin >> 6, vrow = vlin & 63;
  const size_t vsrc0 = (size_t)vd * (SS * 2) + vrow;

  // ds_read fragment byte offsets
  int koff[2][2], voff[4];
#pragma unroll
  for (int f = 0; f < 2; f++)
#pragma unroll
    for (int kk = 0; kk < 2; kk++)
      koff[f][kk] = (((ln + 16 * f) * 128) + kk * 64 + 16 * g) ^ ((ln & 7) << 4);
#pragma unroll
  for (int fd = 0; fd < 4; fd++) {
    const int d = ln + 16 * fd;
    voff[fd] = (d * 64 + 16 * g) ^ (((d >> 1) & 3) << 4);
  }
  char* pw1 = smP1[wid];
  char* pw2 = smP2[wid];

  float ls[4] = {0.f, 0.f, 0.f, 0.f}, lis[4] = {0.f, 0.f, 0.f, 0.f};

  // ---- PASS 1: row sums of exp(energy) (max-free; logits are O(1)) ----
  for (int s0 = 0; s0 < SS; s0 += 32) {
    __syncthreads();
    gload16(Kb + (size_t)s0 * 128 + klin, smK + beta);
    gload16(Kib + (size_t)s0 * 128 + klin, smKi + beta);
    __syncthreads();
    const float kf0 = mb[s0 + ln] != 0 ? 1.f : 0.f;
    const float kf1 = mb[s0 + ln + 16] != 0 ? 1.f : 0.f;
    f32x4 e0 = {0.f, 0.f, 0.f, 0.f}, e1 = {0.f, 0.f, 0.f, 0.f};
    e0 = MFMA(aq0, *(const s16x8*)(smK + koff[0][0]), e0);
    e0 = MFMA(aq1, *(const s16x8*)(smK + koff[0][1]), e0);
    e1 = MFMA(aq0, *(const s16x8*)(smK + koff[1][0]), e1);
    e1 = MFMA(aq1, *(const s16x8*)(smK + koff[1][1]), e1);
    f32x4 t0 = {0.f, 0.f, 0.f, 0.f}, t1 = {0.f, 0.f, 0.f, 0.f};
    t0 = MFMA(ai0, *(const s16x8*)(smKi + koff[0][0]), t0);
    t0 = MFMA(ai1, *(const s16x8*)(smKi + koff[0][1]), t0);
    t1 = MFMA(ai0, *(const s16x8*)(smKi + koff[1][0]), t1);
    t1 = MFMA(ai1, *(const s16x8*)(smKi + koff[1][1]), t1);
#pragma unroll
    for (int r = 0; r < 4; r++) {
      ls[r] += kf0 * __expf(e0[r]) + kf1 * __expf(e1[r]);
      lis[r] += kf0 * __expf(t0[r]) + kf1 * __expf(t1[r]);
    }
  }
#pragma unroll
  for (int off = 1; off < 16; off <<= 1) {
#pragma unroll
    for (int r = 0; r < 4; r++) {
      ls[r] += __shfl_xor(ls[r], off);
      lis[r] += __shfl_xor(lis[r], off);
    }
  }
  float linv[4], liinv[4];
#pragma unroll
  for (int r = 0; r < 4; r++) {
    linv[r] = 1.f / ls[r];
    liinv[r] = 1.f / lis[r];
  }

  // ---- PASS 2: recompute, write attn, accumulate PV for both paths ----
  f32x4 xa[4];
#pragma unroll
  for (int fd = 0; fd < 4; fd++) xa[fd] = {0.f, 0.f, 0.f, 0.f};

  const size_t abase0 = ((((size_t)b * NHEADS + h) * SS) + q0 + 4 * g) * SS + ln;

  for (int s0 = 0; s0 < SS; s0 += 32) {
    __syncthreads();
    gload16(Kb + (size_t)s0 * 128 + klin, smK + beta);
    gload16(Kib + (size_t)s0 * 128 + klin, smKi + beta);
    gload16(Vb + vsrc0 + (size_t)s0 * 2, smV + beta);
    gload16(Vib + vsrc0 + (size_t)s0 * 2, smVi + beta);
    __syncthreads();
    const float kf0 = mb[s0 + ln] != 0 ? 1.f : 0.f;
    const float kf1 = mb[s0 + ln + 16] != 0 ? 1.f : 0.f;

    // path 1 (writes attn output)
    {
      f32x4 e0 = {0.f, 0.f, 0.f, 0.f}, e1 = {0.f, 0.f, 0.f, 0.f};
      e0 = MFMA(aq0, *(const s16x8*)(smK + koff[0][0]), e0);
      e0 = MFMA(aq1, *(const s16x8*)(smK + koff[0][1]), e0);
      e1 = MFMA(aq0, *(const s16x8*)(smK + koff[1][0]), e1);
      e1 = MFMA(aq1, *(const s16x8*)(smK + koff[1][1]), e1);
      float p0[4], p1[4];
#pragma unroll
      for (int r = 0; r < 4; r++) {
        p0[r] = kf0 * __expf(e0[r]) * linv[r];
        p1[r] = kf1 * __expf(e1[r]) * linv[r];
      }
#pragma unroll
      for (int r = 0; r < 4; r++) {
        attn_out[abase0 + (size_t)r * SS + s0] = p0[r];
        attn_out[abase0 + (size_t)r * SS + s0 + 16] = p1[r];
      }
#pragma unroll
      for (int r = 0; r < 4; r++) {
        *(unsigned short*)(pw1 + (4 * g + r) * 80 + ln * 2) = f2bf(p0[r]);
        *(unsigned short*)(pw1 + (4 * g + r) * 80 + (ln + 16) * 2) = f2bf(p1[r]);
      }
      const s16x8 pa = *(const s16x8*)(pw1 + ln * 80 + 16 * g);
#pragma unroll
      for (int fd = 0; fd < 4; fd++)
        xa[fd] = MFMA(pa, *(const s16x8*)(smV + voff[fd]), xa[fd]);
    }
    // path 2 (iteration attention, not an output)
    {
      f32x4 t0 = {0.f, 0.f, 0.f, 0.f}, t1 = {0.f, 0.f, 0.f, 0.f};
      t0 = MFMA(ai0, *(const s16x8*)(smKi + koff[0][0]), t0);
      t0 = MFMA(ai1, *(const s16x8*)(smKi + koff[0][1]), t0);
      t1 = MFMA(ai0, *(const s16x8*)(smKi + koff[1][0]), t1);
      t1 = MFMA(ai1, *(const s16x8*)(smKi + koff[1][1]), t1);
      float p0[4], p1[4];
#pragma unroll
      for (int r = 0; r < 4; r++) {
        p0[r] = kf0 * __expf(t0[r]) * liinv[r];
        p1[r] = kf1 * __expf(t1[r]) * liinv[r];
      }
#pragma unroll
      for (int r = 0; r < 4; r++) {
        *(unsigned short*)(pw2 + (4 * g + r) * 80 + ln * 2) = f2bf(p0[r]);
        *(unsigned short*)(pw2 + (4 * g + r) * 80 + (ln + 16) * 2) = f2bf(p1[r]);
      }
      const s16x8 pa = *(const s16x8*)(pw2 + ln * 80 + 16 * g);
#pragma unroll
      for (int fd = 0; fd < 4; fd++)
        xa[fd] = MFMA(pa, *(const s16x8*)(smVi + voff[fd]), xa[fd]);
    }
  }

  // epilogue: X[b*S+q][h*64+d] bf16
  const size_t xbase = ((size_t)(b * SS + q0 + 4 * g)) * HID + h * HDIM + ln;
#pragma unroll
  for (int fd = 0; fd < 4; fd++)
#pragma unroll
    for (int r = 0; r < 4; r++)
      X[xbase + (size_t)r * HID + fd * 16] = f2bf(xa[fd][r]);
}

// ---------------- host ----------------
extern "C" void kernel_launch(void* const* d_in, const int* in_sizes, int n_in,
                              void* d_out, int out_size, void* d_ws, size_t ws_size,
                              hipStream_t stream) {
  const float* query = (const float*)d_in[0];
  const float* key = (const float*)d_in[1];
  const float* value = (const float*)d_in[2];
  const float* iteration = (const float*)d_in[3];
  const int* mask = (const int*)d_in[4];
  const float* Wq = (const float*)d_in[5];
  const float* bq = (const float*)d_in[6];
  const float* Wk = (const float*)d_in[7];
  const float* bk = (const float*)d_in[8];
  const float* Wv = (const float*)d_in[9];
  const float* bv = (const float*)d_in[10];
  const float* Wiq = (const float*)d_in[11];
  const float* biq = (const float*)d_in[12];
  const float* Wik = (const float*)d_in[13];
  const float* bik = (const float*)d_in[14];
  const float* Wiv = (const float*)d_in[15];
  const float* biv = (const float*)d_in[16];
  const float* Wo = (const float*)d_in[17];
  const float* bo = (const float*)d_in[18];

  char* w = (char*)d_ws;
  auto alloc = [&](size_t bytes) {
    char* p = w;
    w += (bytes + 255) & ~(size_t)255;
    return p;
  };
  const size_t big = (size_t)MROWS * HID * 2;        // 16 MiB bf16
  const size_t small = (size_t)MROWS * HDIM * 2;     // 1 MiB bf16
  unsigned short* qb = (unsigned short*)alloc(big);
  unsigned short* kb = (unsigned short*)alloc(big);
  unsigned short* vb = (unsigned short*)alloc(big);
  unsigned short* ib = (unsigned short*)alloc(big);
  unsigned short* WqT = (unsigned short*)alloc((size_t)HID * HID * 2);
  unsigned short* WiqT = (unsigned short*)alloc((size_t)HID * HID * 2);
  unsigned short* WoT = (unsigned short*)alloc((size_t)HID * HID * 2);
  unsigned short* WkT = (unsigned short*)alloc((size_t)HDIM * HID * 2);
  unsigned short* WvT = (unsigned short*)alloc((size_t)HDIM * HID * 2);
  unsigned short* WikT = (unsigned short*)alloc((size_t)HDIM * HID * 2);
  unsigned short* WivT = (unsigned short*)alloc((size_t)HDIM * HID * 2);
  unsigned short* Qw = (unsigned short*)alloc(big);
  unsigned short* Qiw = (unsigned short*)alloc(big);
  unsigned short* Kw = (unsigned short*)alloc(small);
  unsigned short* Kiw = (unsigned short*)alloc(small);
  unsigned short* VTw = (unsigned short*)alloc(small);
  unsigned short* ViTw = (unsigned short*)alloc(small);
  unsigned short* Xw = (unsigned short*)alloc(big);

  const int n4 = MROWS * HID / 4;
  to_bf16<<<2048, 256, 0, stream>>>(query, qb, n4);
  to_bf16<<<2048, 256, 0, stream>>>(key, kb, n4);
  to_bf16<<<2048, 256, 0, stream>>>(value, vb, n4);
  to_bf16<<<2048, 256, 0, stream>>>(iteration, ib, n4);

  dim3 tb(32, 8);
  transpose_w<<<dim3(32, 32), tb, 0, stream>>>(Wq, WqT, HID, HID);
  transpose_w<<<dim3(32, 32), tb, 0, stream>>>(Wiq, WiqT, HID, HID);
  transpose_w<<<dim3(32, 32), tb, 0, stream>>>(Wo, WoT, HID, HID);
  transpose_w<<<dim3(2, 32), tb, 0, stream>>>(Wk, WkT, HID, HDIM);
  transpose_w<<<dim3(2, 32), tb, 0, stream>>>(Wv, WvT, HID, HDIM);
  transpose_w<<<dim3(2, 32), tb, 0, stream>>>(Wik, WikT, HID, HDIM);
  transpose_w<<<dim3(2, 32), tb, 0, stream>>>(Wiv, WivT, HID, HDIM);

  // Q/Qi projections, pre-scaled by 1/sqrt(HDIM)=1/8
  gemm_bt_128<0><<<dim3(64, 8), 256, 0, stream>>>(qb, WqT, bq, Qw, 0.125f);
  gemm_bt_128<0><<<dim3(64, 8), 256, 0, stream>>>(ib, WiqT, biq, Qiw, 0.125f);
  // K/Ki row-major, V/Vi transposed
  gemm_bt_64<0><<<64, 256, 0, stream>>>(kb, WkT, bk, Kw);
  gemm_bt_64<0><<<64, 256, 0, stream>>>(ib, WikT, bik, Kiw);
  gemm_bt_64<1><<<64, 256, 0, stream>>>(vb, WvT, bv, VTw);
  gemm_bt_64<1><<<64, 256, 0, stream>>>(vb, WivT, biv, ViTw);

  float* out_x = (float*)d_out;
  float* out_attn = out_x + (size_t)MROWS * HID;
  attn_kernel<<<dim3(32, 16, 4), 256, 0, stream>>>(Qw, Qiw, Kw, Kiw, VTw, ViTw,
                                                   mask, out_attn, Xw);
  // final projection: fp32 out with bias
  gemm_bt_128<1><<<dim3(64, 8), 256, 0, stream>>>(Xw, WoT, bo, (void*)out_x, 1.0f);
}